// Round 15
// baseline (158.082 us; speedup 1.0000x reference)
//
#include <hip/hip_runtime.h>
#include <math.h>

#define HEADS 4
#define DHEAD 128
#define NPOS  4096      // 64*64 spatial positions
#define CIN   256
#define SCALEF 0.08838834764831845f   // 128^-0.5
#define LOG2E  1.4426950408889634f
#define QSCALE (SCALEF * LOG2E)       // folded: exp(sim) == exp2(sim * log2e)

typedef _Float16 half8  __attribute__((ext_vector_type(8)));
typedef _Float16 half4  __attribute__((ext_vector_type(4)));
typedef _Float16 half2v __attribute__((ext_vector_type(2)));
typedef float    f32x4  __attribute__((ext_vector_type(4)));
typedef int      i32x4  __attribute__((ext_vector_type(4)));

// Fragment layout for a matrix consumed as a 16x16x32 MFMA operand:
//   frag[rowtile = row>>4][kb = col>>5][lane = ((col>>3)&3)*16 + (row&15)][elem = col&7]
// One (rowtile,kb) slab = 64 lanes * 8 halves = 1 KiB contiguous.
#define FRAG_HEAD_HALVES (256 * 4 * 512)   // 524288 halves = 1 MB per head

// ---------------------------------------------------------------------------
// Kernel 1 (fused cvt+proj): qk[o][p] = sum_c W[o][c]*fmap[c][p], fp16 MFMA.
// fmap tile transposed to fp16 [p][c] through LDS in-block; W converted to
// fp16 (with QSCALE on Q rows) inline at fragment build.  Output written in
// FRAGMENT layout (qf / kf) for the attn kernel.
// ---------------------------------------------------------------------------
__global__ __launch_bounds__(256) void proj_fused(const float* __restrict__ fmap,
                                                  const float* __restrict__ W,
                                                  _Float16* __restrict__ qf,
                                                  _Float16* __restrict__ kf) {
  const int p0 = blockIdx.x * 64;
  const int o0 = blockIdx.y * 64 + (threadIdx.x >> 6) * 16;
  const int wv = threadIdx.x >> 6;
  const int l = threadIdx.x & 63;
  const int lr = l & 15, lg = l >> 4;

  __shared__ _Float16 fstage[64 * 258];   // [p][c] fp16, row stride 258 halves

  // stage: wave wv converts c-rows wv*64 .. wv*64+63, transposed into fstage.
  // b32 writes at byte stride 516: bank = (l + c/2) % 32 -> 2-way (free).
  {
    const int cb0 = wv * 64;
#pragma unroll
    for (int cb = 0; cb < 32; ++cb) {
      int c = cb0 + cb * 2;
      float f0 = fmap[(size_t)(c + 0) * NPOS + p0 + l];
      float f1 = fmap[(size_t)(c + 1) * NPOS + p0 + l];
      half2v hv = {(_Float16)f0, (_Float16)f1};
      *(half2v*)&fstage[l * 258 + c] = hv;
    }
  }
  __syncthreads();

  const float sc = (o0 + lr) < 512 ? QSCALE : 1.0f;
  const f32x4 z = {0.f, 0.f, 0.f, 0.f};
  f32x4 acc[4] = {z, z, z, z};
#pragma unroll
  for (int kb = 0; kb < 8; ++kb) {
    const float* wp = W + (size_t)(o0 + lr) * CIN + kb * 32 + lg * 8;
    f32x4 w0 = *(const f32x4*)wp;
    f32x4 w1 = *(const f32x4*)(wp + 4);
    half8 a = {(_Float16)(w0[0] * sc), (_Float16)(w0[1] * sc),
               (_Float16)(w0[2] * sc), (_Float16)(w0[3] * sc),
               (_Float16)(w1[0] * sc), (_Float16)(w1[1] * sc),
               (_Float16)(w1[2] * sc), (_Float16)(w1[3] * sc)};
#pragma unroll
    for (int j = 0; j < 4; ++j) {
      const _Float16* bp = &fstage[(j * 16 + lr) * 258 + kb * 32 + lg * 8];
      i32x4 iv;
      iv[0] = *(const int*)(bp);
      iv[1] = *(const int*)(bp + 2);
      iv[2] = *(const int*)(bp + 4);
      iv[3] = *(const int*)(bp + 6);
      half8 bfr;
      __builtin_memcpy(&bfr, &iv, 16);
      acc[j] = __builtin_amdgcn_mfma_f32_16x16x32_f16(a, bfr, acc[j], 0, 0, 0);
    }
  }
  // C/D: col(p) = lr, row(o) = lg*4 + r.  4 consecutive d per lane.
  const int ob = o0 + lg * 4;
  const bool isq = ob < 512;
  const int oo = isq ? ob : ob - 512;
  const int h = oo >> 7, db = oo & 127;        // d base, multiple of 4
  const int kb2 = db >> 5;                     // frag kb
  const int flane = ((db >> 3) & 3) * 16 + lr; // frag lane (lr = p&15)
  const int e0 = db & 7;                       // 0 or 4
  _Float16* dst = (isq ? qf : kf) + (size_t)h * FRAG_HEAD_HALVES;
#pragma unroll
  for (int j = 0; j < 4; ++j) {
    int pt = (p0 >> 4) + j;                    // position tile
    half4 v = {(_Float16)acc[j][0], (_Float16)acc[j][1],
               (_Float16)acc[j][2], (_Float16)acc[j][3]};
    *(half4*)(dst + ((size_t)pt * 4 + kb2) * 512 + flane * 8 + e0) = v;
  }
}

// ---------------------------------------------------------------------------
// Kernel 2: fused sim + softmax, TWO-PASS RECOMPUTE (no P storage).
// R12 scaffolding (512 thr / 8 waves / 512-col strips, DMA-staged K with
// counted vmcnt(4), XCD swizzle, exp2, setprio) but: pass 1 computes row
// sums only; pass 2 recomputes each tile and stores it IMMEDIATELY (one
// dwordx4 per tile per lane, swapped-operand C layout) -> output stores are
// spread uniformly through pass 2's compute instead of bursting at the end.
// ---------------------------------------------------------------------------
#define QROWS 16
#define NTIL  32

__global__ __launch_bounds__(512) void attn_mfma(const _Float16* __restrict__ qf,
                                                 const _Float16* __restrict__ kf,
                                                 float* __restrict__ out) {
  // XCD-locality decode (bijective: 1024 blocks, 1024 % 8 == 0)
  const int b = blockIdx.x;            // 0..1023
  const int h = (b & 7) >> 1;          // head on XCD pair {2h, 2h+1}
  const int qtile = ((b >> 3) << 1) | (b & 1);   // 0..255, bijective per head
  const int i0 = qtile * QROWS;

  const int wv = threadIdx.x >> 6;
  const int l = threadIdx.x & 63;
  const int lr = l & 15, lg = l >> 4;

  __shared__ __align__(16) _Float16 kstage[2][8][2048];  // 64 KB dbuf staging
  __shared__ float red[8][16];

  const _Float16* Qf = qf + (size_t)h * FRAG_HEAD_HALVES;
  const _Float16* Kf = kf + (size_t)h * FRAG_HEAD_HALVES;

  // Q fragments (B operand of swapped MFMA), hoisted for whole kernel
  half8 qfr[4];
#pragma unroll
  for (int kb = 0; kb < 4; ++kb)
    qfr[kb] = *(const half8*)(Qf + ((size_t)(i0 >> 4) * 4 + kb) * 512 + l * 8);

  const int jt0 = wv * NTIL;      // first column tile for this wave
  const _Float16* kbase = Kf + (size_t)jt0 * 2048 + l * 8;  // per-lane addr

  float rs = 0.f;
  const f32x4 z = {0.f, 0.f, 0.f, 0.f};

#define DMA(buf, tt)                                                          \
  { const _Float16* kp_ = kbase + (size_t)(tt) * 2048;                        \
    __builtin_amdgcn_global_load_lds(                                         \
        (const __attribute__((address_space(1))) unsigned int*)(kp_),         \
        (__attribute__((address_space(3))) unsigned int*)(&kstage[buf][wv][0]), 16, 0, 0);  \
    __builtin_amdgcn_global_load_lds(                                         \
        (const __attribute__((address_space(1))) unsigned int*)(kp_ + 512),   \
        (__attribute__((address_space(3))) unsigned int*)(&kstage[buf][wv][512]), 16, 0, 0); \
    __builtin_amdgcn_global_load_lds(                                         \
        (const __attribute__((address_space(1))) unsigned int*)(kp_ + 1024),  \
        (__attribute__((address_space(3))) unsigned int*)(&kstage[buf][wv][1024]), 16, 0, 0); \
    __builtin_amdgcn_global_load_lds(                                         \
        (const __attribute__((address_space(1))) unsigned int*)(kp_ + 1536),  \
        (__attribute__((address_space(3))) unsigned int*)(&kstage[buf][wv][1536]), 16, 0, 0); }

  // acc[r] (lane lr,lg) = sim[q-row i0+lr][k-col (jt0+t)*16 + lg*4 + r]
#define QKT(buf)                                                              \
    const _Float16* sp = &kstage[buf][wv][l * 8];                             \
    half8 b0 = *(const half8*)(sp);                                           \
    half8 b1 = *(const half8*)(sp + 512);                                     \
    half8 b2 = *(const half8*)(sp + 1024);                                    \
    half8 b3 = *(const half8*)(sp + 1536);                                    \
    f32x4 acc = z;                                                            \
    __builtin_amdgcn_s_setprio(1);                                            \
    acc = __builtin_amdgcn_mfma_f32_16x16x32_f16(b0, qfr[0], acc, 0, 0, 0);   \
    acc = __builtin_amdgcn_mfma_f32_16x16x32_f16(b1, qfr[1], acc, 0, 0, 0);   \
    acc = __builtin_amdgcn_mfma_f32_16x16x32_f16(b2, qfr[2], acc, 0, 0, 0);   \
    acc = __builtin_amdgcn_mfma_f32_16x16x32_f16(b3, qfr[3], acc, 0, 0, 0);   \
    __builtin_amdgcn_s_setprio(0);

#define SUM(buf)                                                              \
  { QKT(buf)                                                                  \
    rs += (__builtin_amdgcn_exp2f(acc[0]) + __builtin_amdgcn_exp2f(acc[1]))   \
        + (__builtin_amdgcn_exp2f(acc[2]) + __builtin_amdgcn_exp2f(acc[3])); }

  // ---------------- pass 1: row sums only ----------------
  DMA(0, 0)
#pragma unroll
  for (int tp = 0; tp < NTIL; tp += 2) {
    DMA(1, tp + 1)
    asm volatile("s_waitcnt vmcnt(4)" ::: "memory");
    SUM(0)
    if (tp + 2 < NTIL) {
      DMA(0, tp + 2)
      asm volatile("s_waitcnt vmcnt(4)" ::: "memory");
    } else {
      asm volatile("s_waitcnt vmcnt(0)" ::: "memory");
    }
    SUM(1)
  }

  // Row sum for q-row lr: reduce lg-groups then waves.
  rs += __shfl_xor(rs, 16);
  rs += __shfl_xor(rs, 32);
  if (l < 16) red[wv][l] = rs;
  __syncthreads();
  float s = 0.f;
#pragma unroll
  for (int w = 0; w < 8; ++w) s += red[w][lr];
  const float inv = 1.0f / s;

  // ---------------- pass 2: recompute + immediate store ----------------
  float* ob = out + ((size_t)(h * NPOS + i0 + lr)) * NPOS + jt0 * 16 + lg * 4;

#define ST(buf, tt)                                                           \
  { QKT(buf)                                                                  \
    f32x4 v;                                                                  \
    v[0] = __builtin_amdgcn_exp2f(acc[0]) * inv;                              \
    v[1] = __builtin_amdgcn_exp2f(acc[1]) * inv;                              \
    v[2] = __builtin_amdgcn_exp2f(acc[2]) * inv;                              \
    v[3] = __builtin_amdgcn_exp2f(acc[3]) * inv;                              \
    *(f32x4*)&ob[(tt) * 16] = v; }

  DMA(0, 0)
#pragma unroll
  for (int tp = 0; tp < NTIL; tp += 2) {
    DMA(1, tp + 1)
    asm volatile("s_waitcnt vmcnt(4)" ::: "memory");
    ST(0, tp)
    if (tp + 2 < NTIL) {
      DMA(0, tp + 2)
      asm volatile("s_waitcnt vmcnt(4)" ::: "memory");
    } else {
      asm volatile("s_waitcnt vmcnt(0)" ::: "memory");
    }
    ST(1, tp + 1)
  }
#undef DMA
#undef QKT
#undef SUM
#undef ST
}

extern "C" void kernel_launch(void* const* d_in, const int* in_sizes, int n_in,
                              void* d_out, int out_size, void* d_ws, size_t ws_size,
                              hipStream_t stream) {
  const float* fmap = (const float*)d_in[0];   // [1,256,64,64]
  const float* W    = (const float*)d_in[1];   // [1024,256]
  float* out = (float*)d_out;                  // [1,4,4096,4096]

  char* ws = (char*)d_ws;
  _Float16* qf = (_Float16*)(ws);                 // 4 MB fragment layout
  _Float16* kf = (_Float16*)(ws + (4u << 20));    // 4 MB fragment layout

  proj_fused<<<dim3(NPOS / 64, 1024 / 64), 256, 0, stream>>>(fmap, W, qf, kf);
  attn_mfma<<<NPOS / QROWS * HEADS, 512, 0, stream>>>(qf, kf, out);
}

// Round 16
// 149.441 us; speedup vs baseline: 1.0578x; 1.0578x over previous
//
#include <hip/hip_runtime.h>
#include <math.h>

#define HEADS 4
#define DHEAD 128
#define NPOS  4096      // 64*64 spatial positions
#define CIN   256
#define SCALEF 0.08838834764831845f   // 128^-0.5
#define LOG2E  1.4426950408889634f
#define QSCALE (SCALEF * LOG2E)       // folded: exp(sim) == exp2(sim * log2e)

typedef _Float16 half8  __attribute__((ext_vector_type(8)));
typedef _Float16 half4  __attribute__((ext_vector_type(4)));
typedef _Float16 half2v __attribute__((ext_vector_type(2)));
typedef float    f32x4  __attribute__((ext_vector_type(4)));

// Fragment layout for a matrix consumed as a 16x16x32 MFMA operand:
//   frag[rowtile = row>>4][kb = col>>5][lane = ((col>>3)&3)*16 + (row&15)][elem = col&7]
// One (rowtile,kb) slab = 64 lanes * 8 halves = 1 KiB contiguous.
#define FRAG_HEAD_HALVES (256 * 4 * 512)   // 524288 halves = 1 MB per head

// ---------------------------------------------------------------------------
// Kernel 0: convert W -> fp16 (QSCALE folded into Q rows), fmap -> fp16
// transposed [p][c] for proj's B-operand.  (R12 version: fusion was neutral.)
// ---------------------------------------------------------------------------
__global__ __launch_bounds__(256) void cvt_kernel(const float* __restrict__ fmap,
                                                  const float* __restrict__ W,
                                                  _Float16* __restrict__ W16,
                                                  _Float16* __restrict__ fmapT) {
  if (blockIdx.x < 16) {
    int base = blockIdx.x * 16384 + threadIdx.x;
#pragma unroll
    for (int t = 0; t < 64; ++t) {
      int idx = base + t * 256;
      float v = W[idx];
      W16[idx] = (_Float16)(idx < 512 * CIN ? v * QSCALE : v);
    }
  } else {
    int tile = blockIdx.x - 16;       // 64 p-tiles x 4 c-tiles
    int p0 = (tile >> 2) * 64, c0 = (tile & 3) * 64;
    __shared__ float t_lds[64][65];
    int tid = threadIdx.x;
#pragma unroll
    for (int t = 0; t < 16; ++t) {
      int lin = tid + t * 256;
      int r = lin >> 6, col = lin & 63;
      t_lds[r][col] = fmap[(size_t)(c0 + r) * NPOS + p0 + col];
    }
    __syncthreads();
#pragma unroll
    for (int t = 0; t < 16; ++t) {
      int lin = tid + t * 256;
      int pr = lin >> 6, cc = lin & 63;
      fmapT[(size_t)(p0 + pr) * CIN + c0 + cc] = (_Float16)t_lds[cc][pr];
    }
  }
}

// ---------------------------------------------------------------------------
// Kernel 1: projection GEMM.  qk[o][p] = sum_c W16[o][c]*fmapT[p][c]
// Output written in FRAGMENT layout (qf / kf) for the attn kernel.
// ---------------------------------------------------------------------------
__global__ __launch_bounds__(256) void proj_mfma(const _Float16* __restrict__ W16,
                                                 const _Float16* __restrict__ fmapT,
                                                 _Float16* __restrict__ qf,
                                                 _Float16* __restrict__ kf) {
  const int p0 = blockIdx.x * 64;
  const int o0 = blockIdx.y * 64 + (threadIdx.x >> 6) * 16;
  const int l = threadIdx.x & 63;
  const int lr = l & 15, lg = l >> 4;

  const f32x4 z = {0.f, 0.f, 0.f, 0.f};
  f32x4 acc[4] = {z, z, z, z};
#pragma unroll
  for (int kb = 0; kb < 8; ++kb) {
    half8 a = *(const half8*)(W16 + (size_t)(o0 + lr) * CIN + kb * 32 + lg * 8);
#pragma unroll
    for (int j = 0; j < 4; ++j) {
      half8 b = *(const half8*)(fmapT + (size_t)(p0 + j * 16 + lr) * CIN + kb * 32 + lg * 8);
      acc[j] = __builtin_amdgcn_mfma_f32_16x16x32_f16(a, b, acc[j], 0, 0, 0);
    }
  }
  // C/D: col(p) = lr, row(o) = lg*4 + r.  4 consecutive d per lane.
  const int ob = o0 + lg * 4;
  const bool isq = ob < 512;
  const int oo = isq ? ob : ob - 512;
  const int h = oo >> 7, db = oo & 127;        // d base, multiple of 4
  const int kb2 = db >> 5;                     // frag kb
  const int flane = ((db >> 3) & 3) * 16 + lr; // frag lane (lr = p&15)
  const int e0 = db & 7;                       // 0 or 4
  _Float16* dst = (isq ? qf : kf) + (size_t)h * FRAG_HEAD_HALVES;
#pragma unroll
  for (int j = 0; j < 4; ++j) {
    int pt = (p0 >> 4) + j;                    // position tile
    half4 v = {(_Float16)acc[j][0], (_Float16)acc[j][1],
               (_Float16)acc[j][2], (_Float16)acc[j][3]};
    *(half4*)(dst + ((size_t)pt * 4 + kb2) * 512 + flane * 8 + e0) = v;
  }
}

// ---------------------------------------------------------------------------
// Kernel 2: fused sim + softmax, QROWS=32 single pass.
// 1024 thr / 16 waves; wave owns a 256-col strip (NTIL=16) and BOTH 16-row
// tiles -> each DMA-staged K tile feeds 8 MFMAs; K L2 traffic halves
// (512 blocks x 1 MB).  P packed fp16 (64 VGPR both tiles).  Swapped-operand
// C layout (R14): lane holds 4 consecutive cols of one row -> scalar row-sum,
// dwordx4 stores.  __launch_bounds__(1024,4) pins the 128-VGPR cap.
// ---------------------------------------------------------------------------
#define QROWS 32
#define NTIL  16

__global__ __launch_bounds__(1024, 4) void attn_mfma(const _Float16* __restrict__ qf,
                                                     const _Float16* __restrict__ kf,
                                                     float* __restrict__ out) {
  // XCD-locality decode (bijective: 512 blocks, 512 % 8 == 0)
  const int b = blockIdx.x;            // 0..511
  const int h = (b & 7) >> 1;          // head on XCD pair {2h, 2h+1}
  const int qt = ((b >> 3) << 1) | (b & 1);   // 0..127, bijective per head
  const int i0 = qt * QROWS;

  const int wv = threadIdx.x >> 6;     // 0..15
  const int l = threadIdx.x & 63;
  const int lr = l & 15, lg = l >> 4;

  __shared__ __align__(16) _Float16 kstage[2][16][2048];  // 128 KB dbuf staging
  __shared__ float red[16][32];

  const _Float16* Qf = qf + (size_t)h * FRAG_HEAD_HALVES;
  const _Float16* Kf = kf + (size_t)h * FRAG_HEAD_HALVES;

  // Q fragments (B operand of swapped MFMA) for both row-tiles, hoisted.
  const int rt0 = i0 >> 4;             // first row-tile index
  half8 qfrA[4], qfrB[4];
#pragma unroll
  for (int kb = 0; kb < 4; ++kb) {
    qfrA[kb] = *(const half8*)(Qf + ((size_t)rt0 * 4 + kb) * 512 + l * 8);
    qfrB[kb] = *(const half8*)(Qf + ((size_t)(rt0 + 1) * 4 + kb) * 512 + l * 8);
  }

  const int jt0 = wv * NTIL;           // first column tile for this wave
  const _Float16* kbase = Kf + (size_t)jt0 * 2048 + l * 8;  // per-lane addr

  half2v PA[2 * NTIL];                 // 32 VGPR
  half2v PB[2 * NTIL];                 // 32 VGPR
  float rsA = 0.f, rsB = 0.f;
  const f32x4 z = {0.f, 0.f, 0.f, 0.f};

#define DMA(buf, tt)                                                          \
  { const _Float16* kp_ = kbase + (size_t)(tt) * 2048;                        \
    __builtin_amdgcn_global_load_lds(                                         \
        (const __attribute__((address_space(1))) unsigned int*)(kp_),         \
        (__attribute__((address_space(3))) unsigned int*)(&kstage[buf][wv][0]), 16, 0, 0);  \
    __builtin_amdgcn_global_load_lds(                                         \
        (const __attribute__((address_space(1))) unsigned int*)(kp_ + 512),   \
        (__attribute__((address_space(3))) unsigned int*)(&kstage[buf][wv][512]), 16, 0, 0); \
    __builtin_amdgcn_global_load_lds(                                         \
        (const __attribute__((address_space(1))) unsigned int*)(kp_ + 1024),  \
        (__attribute__((address_space(3))) unsigned int*)(&kstage[buf][wv][1024]), 16, 0, 0); \
    __builtin_amdgcn_global_load_lds(                                         \
        (const __attribute__((address_space(1))) unsigned int*)(kp_ + 1536),  \
        (__attribute__((address_space(3))) unsigned int*)(&kstage[buf][wv][1536]), 16, 0, 0); }

  // acc[r] (lane lr,lg) = sim[q-row (rowtile base)+lr][k-col jt*16 + lg*4 + r]
#define COMPUTE(buf, tt)                                                      \
  { const _Float16* sp = &kstage[buf][wv][l * 8];                             \
    half8 b0 = *(const half8*)(sp);                                           \
    half8 b1 = *(const half8*)(sp + 512);                                     \
    half8 b2 = *(const half8*)(sp + 1024);                                    \
    half8 b3 = *(const half8*)(sp + 1536);                                    \
    f32x4 aA = z, aB = z;                                                     \
    __builtin_amdgcn_s_setprio(1);                                            \
    aA = __builtin_amdgcn_mfma_f32_16x16x32_f16(b0, qfrA[0], aA, 0, 0, 0);    \
    aB = __builtin_amdgcn_mfma_f32_16x16x32_f16(b0, qfrB[0], aB, 0, 0, 0);    \
    aA = __builtin_amdgcn_mfma_f32_16x16x32_f16(b1, qfrA[1], aA, 0, 0, 0);    \
    aB = __builtin_amdgcn_mfma_f32_16x16x32_f16(b1, qfrB[1], aB, 0, 0, 0);    \
    aA = __builtin_amdgcn_mfma_f32_16x16x32_f16(b2, qfrA[2], aA, 0, 0, 0);    \
    aB = __builtin_amdgcn_mfma_f32_16x16x32_f16(b2, qfrB[2], aB, 0, 0, 0);    \
    aA = __builtin_amdgcn_mfma_f32_16x16x32_f16(b3, qfrA[3], aA, 0, 0, 0);    \
    aB = __builtin_amdgcn_mfma_f32_16x16x32_f16(b3, qfrB[3], aB, 0, 0, 0);    \
    __builtin_amdgcn_s_setprio(0);                                            \
    float eA0 = __builtin_amdgcn_exp2f(aA[0]);                                \
    float eA1 = __builtin_amdgcn_exp2f(aA[1]);                                \
    float eA2 = __builtin_amdgcn_exp2f(aA[2]);                                \
    float eA3 = __builtin_amdgcn_exp2f(aA[3]);                                \
    float eB0 = __builtin_amdgcn_exp2f(aB[0]);                                \
    float eB1 = __builtin_amdgcn_exp2f(aB[1]);                                \
    float eB2 = __builtin_amdgcn_exp2f(aB[2]);                                \
    float eB3 = __builtin_amdgcn_exp2f(aB[3]);                                \
    rsA += (eA0 + eA1) + (eA2 + eA3);                                         \
    rsB += (eB0 + eB1) + (eB2 + eB3);                                         \
    PA[2 * (tt)]     = half2v{(_Float16)eA0, (_Float16)eA1};                  \
    PA[2 * (tt) + 1] = half2v{(_Float16)eA2, (_Float16)eA3};                  \
    PB[2 * (tt)]     = half2v{(_Float16)eB0, (_Float16)eB1};                  \
    PB[2 * (tt) + 1] = half2v{(_Float16)eB2, (_Float16)eB3}; }

  DMA(0, 0)
#pragma unroll
  for (int tp = 0; tp < NTIL; tp += 2) {
    DMA(1, tp + 1)                                     // NTIL even
    asm volatile("s_waitcnt vmcnt(4)" ::: "memory");   // tile tp landed
    COMPUTE(0, tp)
    if (tp + 2 < NTIL) {
      DMA(0, tp + 2)
      asm volatile("s_waitcnt vmcnt(4)" ::: "memory"); // tile tp+1 landed
    } else {
      asm volatile("s_waitcnt vmcnt(0)" ::: "memory"); // final drain
    }
    COMPUTE(1, tp + 1)
  }
#undef DMA
#undef COMPUTE

  // Row sums: reduce lg-groups (lanes lr, lr+16, lr+32, lr+48) then waves.
  rsA += __shfl_xor(rsA, 16);
  rsA += __shfl_xor(rsA, 32);
  rsB += __shfl_xor(rsB, 16);
  rsB += __shfl_xor(rsB, 32);
  if (l < 16) {
    red[wv][l] = rsA;
    red[wv][16 + l] = rsB;
  }
  __syncthreads();
  float sA = 0.f, sB = 0.f;
#pragma unroll
  for (int w = 0; w < 16; ++w) {
    sA += red[w][lr];
    sB += red[w][16 + lr];
  }
  const float invA = 1.0f / sA;
  const float invB = 1.0f / sB;

  // Normalized write: rowA = i0+lr, rowB = i0+16+lr; cols = (jt0+t)*16+lg*4.
  float* obA = out + ((size_t)(h * NPOS + i0 + lr)) * NPOS + jt0 * 16 + lg * 4;
  float* obB = obA + (size_t)16 * NPOS;
#pragma unroll
  for (int t = 0; t < NTIL; ++t) {
    f32x4 vA, vB;
    vA[0] = (float)PA[2 * t][0] * invA;
    vA[1] = (float)PA[2 * t][1] * invA;
    vA[2] = (float)PA[2 * t + 1][0] * invA;
    vA[3] = (float)PA[2 * t + 1][1] * invA;
    vB[0] = (float)PB[2 * t][0] * invB;
    vB[1] = (float)PB[2 * t][1] * invB;
    vB[2] = (float)PB[2 * t + 1][0] * invB;
    vB[3] = (float)PB[2 * t + 1][1] * invB;
    *(f32x4*)&obA[t * 16] = vA;
    *(f32x4*)&obB[t * 16] = vB;
  }
}

extern "C" void kernel_launch(void* const* d_in, const int* in_sizes, int n_in,
                              void* d_out, int out_size, void* d_ws, size_t ws_size,
                              hipStream_t stream) {
  const float* fmap = (const float*)d_in[0];   // [1,256,64,64]
  const float* W    = (const float*)d_in[1];   // [1024,256]
  float* out = (float*)d_out;                  // [1,4,4096,4096]

  char* ws = (char*)d_ws;
  _Float16* qf    = (_Float16*)(ws);                    // 4 MB fragment layout
  _Float16* kf    = (_Float16*)(ws + (4u << 20));       // 4 MB fragment layout
  _Float16* W16   = (_Float16*)(ws + (8u << 20));       // 512 KB
  _Float16* fmapT = (_Float16*)(ws + (8u << 20) + (512u << 10)); // 2 MB

  cvt_kernel<<<272, 256, 0, stream>>>(fmap, W, W16, fmapT);
  proj_mfma<<<dim3(NPOS / 64, 1024 / 64), 256, 0, stream>>>(W16, fmapT, qf, kf);
  attn_mfma<<<NPOS / QROWS * HEADS, 1024, 0, stream>>>(qf, kf, out);
}